// Round 10
// baseline (10711.407 us; speedup 1.0000x reference)
//
#include <hip/hip_runtime.h>
#include <cstdint>
#include <cstddef>

#define DEVINL __device__ __forceinline__

typedef float f32x4 __attribute__((ext_vector_type(4)));

DEVINL float ntload1(const float* p) {
    return __builtin_nontemporal_load(p);
}
DEVINL f32x4 ld4(const float* p) {
    return *reinterpret_cast<const f32x4*>(p);
}

// ---------- math helpers ----------
DEVINL float frcp(float x) { return __builtin_amdgcn_rcpf(x); }
DEVINL float ftanh_fast(float x) {
    float e = __expf(2.0f * x);
    return 1.0f - 2.0f * frcp(e + 1.0f);
}
DEVINL float sig_precise(float x) { return 1.0f / (1.0f + expf(-x)); }
DEVINL float tanh_precise(float x) { return tanhf(x); }

// ---------- sizes ----------
#define BB 128
#define SS 128
#define IND 16
#define DD 256
#define HH 256
#define H4 1024
#define H2 512

// =====================================================================
// K1: emb = LayerNorm(tanh(x @ proj_W.T + proj_b))   (one block per row)
// =====================================================================
__global__ __launch_bounds__(256) void k_proj_ln(
    const float* __restrict__ x, const float* __restrict__ projW,
    const float* __restrict__ projB, const float* __restrict__ ln_g,
    const float* __restrict__ ln_b, float* __restrict__ emb)
{
    __shared__ float Wl[256 * 17];
    __shared__ float xl[16];
    __shared__ float red[256];
    const int row = blockIdx.x;
    const int tid = threadIdx.x;
    for (int idx = tid; idx < 256 * 16; idx += 256) {
        int d = idx >> 4, i = idx & 15;
        Wl[d * 17 + i] = projW[idx];
    }
    if (tid < 16) xl[tid] = x[row * 16 + tid];
    __syncthreads();
    float acc = projB[tid];
#pragma unroll
    for (int i = 0; i < 16; ++i) acc = fmaf(Wl[tid * 17 + i], xl[i], acc);
    float v = tanh_precise(acc);
    red[tid] = v;
    __syncthreads();
    for (int s2 = 128; s2 > 0; s2 >>= 1) { if (tid < s2) red[tid] += red[tid + s2]; __syncthreads(); }
    float mean = red[0] * (1.0f / 256.0f);
    __syncthreads();
    float dlt = v - mean;
    red[tid] = dlt * dlt;
    __syncthreads();
    for (int s2 = 128; s2 > 0; s2 >>= 1) { if (tid < s2) red[tid] += red[tid + s2]; __syncthreads(); }
    float var = red[0] * (1.0f / 256.0f);
    float rs = 1.0f / sqrtf(var + 1e-5f);
    emb[(size_t)row * 256 + tid] = dlt * rs * ln_g[tid] + ln_b[tid];
}

// =====================================================================
// K2: generic fp32 GEMM-NT  C(MxN) = A(MxK,lda) * B(NxK)^T (+bias1+bias2)
// =====================================================================
__global__ __launch_bounds__(256) void k_gemm_nt(
    const float* __restrict__ A, int lda,
    const float* __restrict__ Bm,
    float* __restrict__ C,
    int M, int N, int K,
    const float* __restrict__ bias1, const float* __restrict__ bias2,
    int flags)
{
    __shared__ __align__(16) float As[16][132];
    __shared__ __align__(16) float Bs[16][132];
    const int tid = threadIdx.x;
    const int m0 = blockIdx.x * 128;
    const int n0 = blockIdx.y * 128;
    const int r = tid >> 1, half = tid & 1;
    const int tm = tid & 15, tn = tid >> 4;
    float acc[8][8];
#pragma unroll
    for (int i = 0; i < 8; ++i)
#pragma unroll
        for (int j = 0; j < 8; ++j) acc[i][j] = 0.0f;

    for (int k0 = 0; k0 < K; k0 += 16) {
        const float4* pa = reinterpret_cast<const float4*>(&A[(size_t)(m0 + r) * lda + k0 + half * 8]);
        float4 a0 = pa[0], a1 = pa[1];
        const float4* pb = reinterpret_cast<const float4*>(&Bm[(size_t)(n0 + r) * K + k0 + half * 8]);
        float4 b0 = pb[0], b1 = pb[1];
        __syncthreads();
        const int kb = half * 8;
        As[kb + 0][r] = a0.x; As[kb + 1][r] = a0.y; As[kb + 2][r] = a0.z; As[kb + 3][r] = a0.w;
        As[kb + 4][r] = a1.x; As[kb + 5][r] = a1.y; As[kb + 6][r] = a1.z; As[kb + 7][r] = a1.w;
        Bs[kb + 0][r] = b0.x; Bs[kb + 1][r] = b0.y; Bs[kb + 2][r] = b0.z; Bs[kb + 3][r] = b0.w;
        Bs[kb + 4][r] = b1.x; Bs[kb + 5][r] = b1.y; Bs[kb + 6][r] = b1.z; Bs[kb + 7][r] = b1.w;
        __syncthreads();
#pragma unroll
        for (int kk = 0; kk < 16; ++kk) {
            const float4 xa0 = *reinterpret_cast<const float4*>(&As[kk][tm * 8]);
            const float4 xa1 = *reinterpret_cast<const float4*>(&As[kk][tm * 8 + 4]);
            const float4 xb0 = *reinterpret_cast<const float4*>(&Bs[kk][tn * 8]);
            const float4 xb1 = *reinterpret_cast<const float4*>(&Bs[kk][tn * 8 + 4]);
            const float av[8] = {xa0.x, xa0.y, xa0.z, xa0.w, xa1.x, xa1.y, xa1.z, xa1.w};
            const float bv[8] = {xb0.x, xb0.y, xb0.z, xb0.w, xb1.x, xb1.y, xb1.z, xb1.w};
#pragma unroll
            for (int i = 0; i < 8; ++i)
#pragma unroll
                for (int j = 0; j < 8; ++j) acc[i][j] = fmaf(av[i], bv[j], acc[i][j]);
        }
    }
    const int nb = n0 + tn * 8;
    float bias[8];
#pragma unroll
    for (int j = 0; j < 8; ++j) {
        float bbv = 0.0f;
        if (bias1) bbv += bias1[nb + j];
        if (bias2) bbv += bias2[nb + j];
        bias[j] = bbv;
    }
#pragma unroll
    for (int i = 0; i < 8; ++i) {
        const size_t m = (size_t)(m0 + tm * 8 + i);
        float o[8];
#pragma unroll
        for (int j = 0; j < 8; ++j) {
            float vv = acc[i][j] + bias[j];
            if (flags & 1) vv = tanh_precise(vv);
            o[j] = vv;
        }
        float4* pc = reinterpret_cast<float4*>(&C[m * N + nb]);
        pc[0] = make_float4(o[0], o[1], o[2], o[3]);
        pc[1] = make_float4(o[4], o[5], o[6], o[7]);
    }
}

// =====================================================================
// K3: bidirectional LSTM, half-block fused: 1024 threads, halves own
// one batch each (2 batches/WG), 4 waves/SIMD. Compact dbuf W-pass.
// grid 128 = 2 dirs * 64 groups.
// =====================================================================
__global__ __launch_bounds__(1024) void k_lstm(
    const float* __restrict__ Whh_f, const float* __restrict__ Whh_b,
    const float* __restrict__ xf, const float* __restrict__ xb,
    float* __restrict__ enc, float* __restrict__ hT, float* __restrict__ cT)
{
    const int wg = blockIdx.x;       // 0..127
    const int dir = wg >> 6;
    const int grp = wg & 63;
    const int bb0 = grp * 2;
    const float* W = dir ? Whh_b : Whh_f;
    const float* xin = dir ? xb : xf;
    const int tid = threadIdx.x;
    const int hb = tid >> 9;          // half-block = batch offset
    const int ht = tid & 511;
    const int oct = ht & 7, jg = ht >> 3;   // jg 0..63
    const int bat = bb0 + hb;

    __shared__ __align__(16) float h_lds[2][256];
    __shared__ float pre_lds[2][1024];

    for (int i = tid; i < 2 * 256; i += 1024) (&h_lds[0][0])[i] = 0.0f;
    float c_reg = 0.0f;
    __syncthreads();

    for (int t = 0; t < SS; ++t) {
        const int st = dir ? (SS - 1 - t) : t;
        float hreg[32];
#pragma unroll
        for (int i = 0; i < 8; ++i) {
            f32x4 v = ld4(&h_lds[hb][i * 32 + oct * 4]);
            hreg[i * 4 + 0] = v.x; hreg[i * 4 + 1] = v.y;
            hreg[i * 4 + 2] = v.z; hreg[i * 4 + 3] = v.w;
        }
        // W pass: 16 q-rounds of 64 rows, 1-ahead dbuf, single batch/half
        {
            f32x4 wA[8], wB[8];
            {
                const float* bp = &W[(size_t)jg * 256 + oct * 4];
#pragma unroll
                for (int i = 0; i < 8; ++i) wA[i] = ld4(bp + i * 32);
            }
            auto wstep = [&](f32x4 (&cur)[8], f32x4 (&nxt)[8], int q) {
                if (q < 15) {
                    const float* bp = &W[(size_t)((q + 1) * 64 + jg) * 256 + oct * 4];
#pragma unroll
                    for (int i = 0; i < 8; ++i) nxt[i] = ld4(bp + i * 32);
                }
                float a0 = 0.0f;
#pragma unroll
                for (int i = 0; i < 8; ++i) {
                    a0 = fmaf(cur[i].x, hreg[i * 4 + 0], a0);
                    a0 = fmaf(cur[i].y, hreg[i * 4 + 1], a0);
                    a0 = fmaf(cur[i].z, hreg[i * 4 + 2], a0);
                    a0 = fmaf(cur[i].w, hreg[i * 4 + 3], a0);
                }
                a0 += __shfl_xor(a0, 1); a0 += __shfl_xor(a0, 2); a0 += __shfl_xor(a0, 4);
                if (oct == 0) pre_lds[hb][q * 64 + jg] = a0;
            };
#pragma unroll 1
            for (int q = 0; q < 16; q += 2) { wstep(wA, wB, q); wstep(wB, wA, q + 1); }
        }
        __syncthreads();
        if (ht < 256) {
            const int gc = ht;
            const float* xrow = &xin[((size_t)bat * SS + st) * 1024];
            float pi = pre_lds[hb][gc]       + ntload1(&xrow[gc]);
            float pf = pre_lds[hb][256 + gc] + ntload1(&xrow[256 + gc]);
            float pg = pre_lds[hb][512 + gc] + ntload1(&xrow[512 + gc]);
            float po = pre_lds[hb][768 + gc] + ntload1(&xrow[768 + gc]);
            float ig = sig_precise(pi), fg = sig_precise(pf);
            float gg = tanh_precise(pg), og = sig_precise(po);
            float cn = fmaf(fg, c_reg, ig * gg);
            float hn = og * tanh_precise(cn);
            c_reg = cn;
            h_lds[hb][gc] = hn;
            enc[((size_t)bat * SS + st) * 512 + dir * 256 + gc] = hn;
            if (t == SS - 1) {
                hT[(size_t)bat * 512 + dir * 256 + gc] = hn;
                cT[(size_t)bat * 512 + dir * 256 + gc] = cn;
            }
        }
        __syncthreads();
    }
}

// =====================================================================
// K5: pre0[b][j] = mean_s encW[b][s][j]
// =====================================================================
__global__ __launch_bounds__(256) void k_meanw(const float* __restrict__ encW, float* __restrict__ pre0)
{
    const int b = blockIdx.x;
    const int tid = threadIdx.x;
    const float4* base = reinterpret_cast<const float4*>(&encW[(size_t)b * SS * 1024]);
    float sx = 0.0f, sy = 0.0f, sz = 0.0f, sw = 0.0f;
    for (int s = 0; s < SS; ++s) {
        float4 v = base[s * 256 + tid];
        sx += v.x; sy += v.y; sz += v.z; sw += v.w;
    }
    float4* out = reinterpret_cast<float4*>(&pre0[(size_t)b * 1024]);
    out[tid] = make_float4(sx * (1.0f / 128.0f), sy * (1.0f / 128.0f), sz * (1.0f / 128.0f), sw * (1.0f / 128.0f));
}

// =====================================================================
// K6: pointer decoder, half-block fused: 64 WGs, 1024 threads;
// threads 0-511 = batch b0, 512-1023 = batch b0+1 (4 waves/SIMD).
// Each half runs the R9 single-batch compact-dbuf phase code.
// =====================================================================
__global__ __launch_bounds__(1024) void k_decoder(
    const float* __restrict__ Whh_d,
    const float* __restrict__ gW2, const float* __restrict__ pW2,
    const float* __restrict__ gv, const float* __restrict__ pv,
    const float* __restrict__ g_ref, const float* __restrict__ p_ref,
    const float* __restrict__ encP, const float* __restrict__ encW,
    const float* __restrict__ pre0, const float* __restrict__ h0,
    const float* __restrict__ c0,
    float* __restrict__ out_logits, float* __restrict__ out_ptrs)
{
    const int b0 = blockIdx.x * 2;
    const int tid = threadIdx.x;
    const int hb = tid >> 9;              // half-block = batch index (0/1)
    const int ht = tid & 511;
    const int oct = ht & 7, jg = ht >> 3; // jg 0..63
    const int hwid = ht >> 6;             // wave-in-half 0..7
    const int lane = tid & 63;

    __shared__ __align__(16) float h_lds[2][256];
    __shared__ float c_lds[2][256];
    __shared__ float pre_lds[2][1024];
    __shared__ float row_lds[2][1024];
    __shared__ __align__(16) float hgp[2][512];   // [.,0..255]=hg, [.,256..511]=hp1
    __shared__ __align__(16) float hp_lds[2][256];
    __shared__ __align__(16) float gv_lds[256];
    __shared__ __align__(16) float pv_lds[256];
    __shared__ float sc_arr[2][128];
    __shared__ float e_arr[2][128];
    __shared__ __align__(16) float hp_half[8][2][256];
    __shared__ int mask_lds[2][128];
    __shared__ float Z_arr[2];
    __shared__ int sel_arr[2];

    if (tid < 256) {
        gv_lds[tid] = gv[tid];
        pv_lds[tid] = pv[tid];
#pragma unroll
        for (int bt = 0; bt < 2; ++bt) {
            h_lds[bt][tid] = h0[(size_t)(b0 + bt) * 256 + tid];
            c_lds[bt][tid] = c0[(size_t)(b0 + bt) * 256 + tid];
        }
    }
    if (tid < 128) { mask_lds[0][tid] = 0; mask_lds[1][tid] = 0; }
    if (tid < 2) sel_arr[tid] = -1;
    __syncthreads();

    for (int t = 0; t < SS; ++t) {
        // ---- stage xt rows (encW[sel] or pre0), both batches ----
#pragma unroll
        for (int rep = 0; rep < 2; ++rep) {
            const int idx = tid + rep * 1024;
            const int btx = idx >> 10, j = idx & 1023;
            const int sel = sel_arr[btx];
            const float* src = (sel < 0) ? &pre0[(size_t)(b0 + btx) * 1024]
                                         : &encW[((size_t)((b0 + btx) * SS + sel)) * 1024];
            row_lds[btx][j] = src[j];
        }
        // h_{t-1} -> regs (own batch)
        float hreg[32];
#pragma unroll
        for (int i = 0; i < 8; ++i) {
            f32x4 v = ld4(&h_lds[hb][i * 32 + oct * 4]);
            hreg[i * 4 + 0] = v.x; hreg[i * 4 + 1] = v.y;
            hreg[i * 4 + 2] = v.z; hreg[i * 4 + 3] = v.w;
        }
        __syncthreads();
        // ---- phase 1: pre = row + Whh_d @ h (16 rounds, compact dbuf) ----
        {
            f32x4 wA[8], wB[8];
            {
                const float* bp = &Whh_d[(size_t)jg * 256 + oct * 4];
#pragma unroll
                for (int i = 0; i < 8; ++i) wA[i] = ld4(bp + i * 32);
            }
            auto p1 = [&](f32x4 (&cur)[8], f32x4 (&nxt)[8], int q) {
                if (q < 15) {
                    const float* bp = &Whh_d[(size_t)((q + 1) * 64 + jg) * 256 + oct * 4];
#pragma unroll
                    for (int i = 0; i < 8; ++i) nxt[i] = ld4(bp + i * 32);
                }
                float a0 = 0.0f;
#pragma unroll
                for (int i = 0; i < 8; ++i) {
                    a0 = fmaf(cur[i].x, hreg[i * 4 + 0], a0);
                    a0 = fmaf(cur[i].y, hreg[i * 4 + 1], a0);
                    a0 = fmaf(cur[i].z, hreg[i * 4 + 2], a0);
                    a0 = fmaf(cur[i].w, hreg[i * 4 + 3], a0);
                }
                a0 += __shfl_xor(a0, 1); a0 += __shfl_xor(a0, 2); a0 += __shfl_xor(a0, 4);
                if (oct == 0) {
                    const int row = q * 64 + jg;
                    pre_lds[hb][row] = a0 + row_lds[hb][row];
                }
            };
#pragma unroll 1
            for (int q = 0; q < 16; q += 2) { p1(wA, wB, q); p1(wB, wA, q + 1); }
        }
        __syncthreads();
        // ---- phase 2: gates (first 256 threads of each half) ----
        if (ht < 256) {
            const int ch = ht;
            float pi = pre_lds[hb][ch],        pf = pre_lds[hb][256 + ch];
            float pg = pre_lds[hb][512 + ch],  po = pre_lds[hb][768 + ch];
            float ig = sig_precise(pi), fg = sig_precise(pf);
            float gg = tanh_precise(pg), og = sig_precise(po);
            float cn = fmaf(fg, c_lds[hb][ch], ig * gg);
            float hn = og * tanh_precise(cn);
            c_lds[hb][ch] = cn;
            h_lds[hb][ch] = hn;
        }
        __syncthreads();
        // reload new h slice
        float hreg2[32];
#pragma unroll
        for (int i = 0; i < 8; ++i) {
            f32x4 v = ld4(&h_lds[hb][i * 32 + oct * 4]);
            hreg2[i * 4 + 0] = v.x; hreg2[i * 4 + 1] = v.y;
            hreg2[i * 4 + 2] = v.z; hreg2[i * 4 + 3] = v.w;
        }
        // ---- phase 3: hg = h@gW2.T (rows 0..255), hp1 = h@pW2.T (256..511) ----
        {
            f32x4 wA[8], wB[8];
            {
                const float* bp = &gW2[(size_t)jg * 256 + oct * 4];
#pragma unroll
                for (int i = 0; i < 8; ++i) wA[i] = ld4(bp + i * 32);
            }
            auto p3 = [&](f32x4 (&cur)[8], f32x4 (&nxt)[8], int q) {
                if (q < 7) {
                    const int r2 = (q + 1) * 64 + jg;
                    const float* src = (r2 < 256) ? &gW2[(size_t)r2 * 256] : &pW2[(size_t)(r2 - 256) * 256];
#pragma unroll
                    for (int i = 0; i < 8; ++i) nxt[i] = ld4(src + oct * 4 + i * 32);
                }
                float a0 = 0.0f;
#pragma unroll
                for (int i = 0; i < 8; ++i) {
                    a0 = fmaf(cur[i].x, hreg2[i * 4 + 0], a0);
                    a0 = fmaf(cur[i].y, hreg2[i * 4 + 1], a0);
                    a0 = fmaf(cur[i].z, hreg2[i * 4 + 2], a0);
                    a0 = fmaf(cur[i].w, hreg2[i * 4 + 3], a0);
                }
                a0 += __shfl_xor(a0, 1); a0 += __shfl_xor(a0, 2); a0 += __shfl_xor(a0, 4);
                if (oct == 0) hgp[hb][q * 64 + jg] = a0;
            };
#pragma unroll 1
            for (int q = 0; q < 8; q += 2) { p3(wA, wB, q); p3(wB, wA, q + 1); }
        }
        __syncthreads();
        // ---- phase 4: gs scores (2 reps, compact dbuf, own batch) ----
        {
            f32x4 gA[8], gB[8];
            {
                const float* gr = &g_ref[((size_t)((b0 + hb) * SS + jg)) * 256 + oct * 4];
#pragma unroll
                for (int i = 0; i < 8; ++i) gA[i] = ld4(gr + i * 32);
            }
            auto p4 = [&](f32x4 (&cur)[8], f32x4 (&nxt)[8], int rep) {
                const int r = jg + (rep << 6);
                if (rep < 1) {
                    const float* gr = &g_ref[((size_t)((b0 + hb) * SS + jg + 64)) * 256 + oct * 4];
#pragma unroll
                    for (int i = 0; i < 8; ++i) nxt[i] = ld4(gr + i * 32);
                }
                float part = 0.0f;
#pragma unroll
                for (int i = 0; i < 8; ++i) {
                    const int d = i * 32 + oct * 4;
                    const f32x4 hh = ld4(&hgp[hb][d]);
                    const f32x4 vv = ld4(&gv_lds[d]);
                    part = fmaf(ftanh_fast(cur[i].x + hh.x), vv.x, part);
                    part = fmaf(ftanh_fast(cur[i].y + hh.y), vv.y, part);
                    part = fmaf(ftanh_fast(cur[i].z + hh.z), vv.z, part);
                    part = fmaf(ftanh_fast(cur[i].w + hh.w), vv.w, part);
                }
                part += __shfl_xor(part, 1); part += __shfl_xor(part, 2); part += __shfl_xor(part, 4);
                if (oct == 0) sc_arr[hb][r] = mask_lds[hb][r] ? -1e9f : part * 0.0625f;
            };
            p4(gA, gB, 0); p4(gB, gA, 1);
        }
        __syncthreads();
        // ---- phase 5: softmax (wave 0 of each half) ----
        if (ht < 64) {
            float s0 = sc_arr[hb][lane], s1 = sc_arr[hb][lane + 64];
            float m = fmaxf(s0, s1);
#pragma unroll
            for (int mk = 1; mk < 64; mk <<= 1) m = fmaxf(m, __shfl_xor(m, mk));
            float e0 = expf(s0 - m), e1 = expf(s1 - m);
            e_arr[hb][lane] = e0; e_arr[hb][lane + 64] = e1;
            float z = e0 + e1;
#pragma unroll
            for (int mk = 1; mk < 64; mk <<= 1) z += __shfl_xor(z, mk);
            if (lane == 0) Z_arr[hb] = z;
        }
        __syncthreads();
        // ---- phase 6: ctx partials (8 waves/half x 16 rows, dbuf) ----
        {
            const int d4 = lane * 4;
            const float* base6 = &encP[((size_t)((b0 + hb) * SS + hwid * 16)) * 256 + d4];
            float ax = 0.0f, ay = 0.0f, az = 0.0f, aw = 0.0f;
            f32x4 pA[8], pB[8];
#pragma unroll
            for (int i = 0; i < 8; ++i) pA[i] = ld4(base6 + i * 256);
            auto p6 = [&](f32x4 (&cur)[8], f32x4 (&nxt)[8], int g) {
                if (g < 1) {
#pragma unroll
                    for (int i = 0; i < 8; ++i) nxt[i] = ld4(base6 + (8 + i) * 256);
                }
#pragma unroll
                for (int i = 0; i < 8; ++i) {
                    const float e = e_arr[hb][hwid * 16 + g * 8 + i];
                    ax = fmaf(cur[i].x, e, ax); ay = fmaf(cur[i].y, e, ay);
                    az = fmaf(cur[i].z, e, az); aw = fmaf(cur[i].w, e, aw);
                }
            };
            p6(pA, pB, 0); p6(pB, pA, 1);
            *reinterpret_cast<float4*>(&hp_half[hwid][hb][d4]) = make_float4(ax, ay, az, aw);
        }
        __syncthreads();
        if (ht < 256) {
            const int d = ht;
            float s = 0.0f;
#pragma unroll
            for (int k = 0; k < 8; ++k) s += hp_half[k][hb][d];
            hp_lds[hb][d] = hgp[hb][256 + d] + s * frcp(Z_arr[hb]);
        }
        __syncthreads();
        // ---- phase 7: ps scores (2 reps, compact dbuf, own batch) ----
        {
            f32x4 gA[8], gB[8];
            {
                const float* pr = &p_ref[((size_t)((b0 + hb) * SS + jg)) * 256 + oct * 4];
#pragma unroll
                for (int i = 0; i < 8; ++i) gA[i] = ld4(pr + i * 32);
            }
            auto p7 = [&](f32x4 (&cur)[8], f32x4 (&nxt)[8], int rep) {
                const int r = jg + (rep << 6);
                if (rep < 1) {
                    const float* pr = &p_ref[((size_t)((b0 + hb) * SS + jg + 64)) * 256 + oct * 4];
#pragma unroll
                    for (int i = 0; i < 8; ++i) nxt[i] = ld4(pr + i * 32);
                }
                float part = 0.0f;
#pragma unroll
                for (int i = 0; i < 8; ++i) {
                    const int d = i * 32 + oct * 4;
                    const f32x4 hh = ld4(&hp_lds[hb][d]);
                    const f32x4 vv = ld4(&pv_lds[d]);
                    part = fmaf(ftanh_fast(cur[i].x + hh.x), vv.x, part);
                    part = fmaf(ftanh_fast(cur[i].y + hh.y), vv.y, part);
                    part = fmaf(ftanh_fast(cur[i].z + hh.z), vv.z, part);
                    part = fmaf(ftanh_fast(cur[i].w + hh.w), vv.w, part);
                }
                part += __shfl_xor(part, 1); part += __shfl_xor(part, 2); part += __shfl_xor(part, 4);
                if (oct == 0) sc_arr[hb][r] = mask_lds[hb][r] ? -1e9f : part * 0.0625f;
            };
            p7(gA, gB, 0); p7(gB, gA, 1);
        }
        __syncthreads();
        // ---- phase 8: logits write + argmax (first-max semantics) ----
        if (ht < 128) {
            out_logits[((size_t)((b0 + hb) * SS + t)) * SS + ht] = sc_arr[hb][ht];
        }
        if (ht < 64) {
            float v = sc_arr[hb][lane];
            int idx = lane;
            float v2 = sc_arr[hb][lane + 64];
            if (v2 > v) { v = v2; idx = lane + 64; }
#pragma unroll
            for (int mk = 1; mk < 64; mk <<= 1) {
                float ov = __shfl_xor(v, mk);
                int oi = __shfl_xor(idx, mk);
                if (ov > v || (ov == v && oi < idx)) { v = ov; idx = oi; }
            }
            if (lane == 0) {
                sel_arr[hb] = idx;
                mask_lds[hb][idx] = 1;
                out_ptrs[(size_t)(b0 + hb) * SS + t] = (float)idx;
            }
        }
        __syncthreads();
    }
}

// =====================================================================
// host launcher
// =====================================================================
extern "C" void kernel_launch(void* const* d_in, const int* in_sizes, int n_in,
                              void* d_out, int out_size, void* d_ws, size_t ws_size,
                              hipStream_t stream)
{
    (void)in_sizes; (void)n_in; (void)out_size; (void)ws_size;
    const float* x      = (const float*)d_in[0];
    const float* proj_W = (const float*)d_in[1];
    const float* proj_b = (const float*)d_in[2];
    const float* ln_g   = (const float*)d_in[3];
    const float* ln_b   = (const float*)d_in[4];
    const float* Wih_f  = (const float*)d_in[5];
    const float* Whh_f  = (const float*)d_in[6];
    const float* bih_f  = (const float*)d_in[7];
    const float* bhh_f  = (const float*)d_in[8];
    const float* Wih_b  = (const float*)d_in[9];
    const float* Whh_b  = (const float*)d_in[10];
    const float* bih_b  = (const float*)d_in[11];
    const float* bhh_b  = (const float*)d_in[12];
    const float* Wih_d  = (const float*)d_in[13];
    const float* Whh_d  = (const float*)d_in[14];
    const float* bih_d  = (const float*)d_in[15];
    const float* bhh_d  = (const float*)d_in[16];
    const float* hb_W   = (const float*)d_in[17];
    const float* hb_b   = (const float*)d_in[18];
    const float* cb_W   = (const float*)d_in[19];
    const float* cb_b   = (const float*)d_in[20];
    const float* gW1    = (const float*)d_in[21];
    const float* gW2    = (const float*)d_in[22];
    const float* gv     = (const float*)d_in[23];
    const float* pW1    = (const float*)d_in[24];
    const float* pW2    = (const float*)d_in[25];
    const float* pv     = (const float*)d_in[26];

    float* ws = (float*)d_ws;
    const size_t o_hT    = 0;
    const size_t o_cT    = 65536;
    const size_t o_h0    = 131072;
    const size_t o_c0    = 163840;
    const size_t o_pre0  = 196608;
    const size_t o_emb   = 0;
    const size_t o_xf    = 4194304;
    const size_t o_xb    = o_xf + 16777216;
    const size_t o_enc   = o_xb + 16777216;
    const size_t o_encW  = o_xf;
    const size_t o_gref  = o_xb;
    const size_t o_pref  = o_xb + 4194304;
    const size_t o_encP  = o_xb + 8388608;

    float* emb  = ws + o_emb;
    float* xf   = ws + o_xf;
    float* xb   = ws + o_xb;
    float* enc  = ws + o_enc;
    float* hT   = ws + o_hT;
    float* cT   = ws + o_cT;
    float* h0b  = ws + o_h0;
    float* c0b  = ws + o_c0;
    float* pre0 = ws + o_pre0;
    float* encW = ws + o_encW;
    float* gref = ws + o_gref;
    float* pref = ws + o_pref;
    float* encP = ws + o_encP;

    float* out_logits = (float*)d_out;
    float* out_ptrs   = out_logits + (size_t)BB * SS * SS;

    // 1. emb
    k_proj_ln<<<BB * SS, 256, 0, stream>>>(x, proj_W, proj_b, ln_g, ln_b, emb);
    // 2-3. xf / xb  (bias = bih + bhh)
    {
        dim3 g(128, 8);
        k_gemm_nt<<<g, 256, 0, stream>>>(emb, 256, Wih_f, xf, 16384, 1024, 256, bih_f, bhh_f, 0);
        k_gemm_nt<<<g, 256, 0, stream>>>(emb, 256, Wih_b, xb, 16384, 1024, 256, bih_b, bhh_b, 0);
    }
    // 4. LSTM both directions (half-block fused, 1024 threads)
    k_lstm<<<128, 1024, 0, stream>>>(Whh_f, Whh_b, xf, xb, enc, hT, cT);
    // 5-6. h0 / c0
    {
        dim3 g(1, 2);
        k_gemm_nt<<<g, 256, 0, stream>>>(hT, 512, hb_W, h0b, 128, 256, 512, hb_b, nullptr, 1);
        k_gemm_nt<<<g, 256, 0, stream>>>(cT, 512, cb_W, c0b, 128, 256, 512, cb_b, nullptr, 1);
    }
    // 7-10. attention precomputes
    {
        dim3 g2(128, 2);
        k_gemm_nt<<<g2, 256, 0, stream>>>(enc, 512, gW1, gref, 16384, 256, 512, nullptr, nullptr, 0);
        k_gemm_nt<<<g2, 256, 0, stream>>>(enc, 512, pW1, pref, 16384, 256, 512, nullptr, nullptr, 0);
        dim3 g1(128, 8);
        k_gemm_nt<<<g1, 256, 0, stream>>>(enc, 512, Wih_d, encW, 16384, 1024, 512, bih_d, bhh_d, 0);
        k_gemm_nt<<<g2, 256, 0, stream>>>(enc, 512, pW2, encP, 16384, 256, 256, nullptr, nullptr, 0);
    }
    // 11. pre0 = mean_s encW
    k_meanw<<<BB, 256, 0, stream>>>(encW, pre0);
    // 12. decoder: 64 WGs x 1024 threads (half-block fused, 4 waves/SIMD)
    k_decoder<<<64, 1024, 0, stream>>>(Whh_d, gW2, pW2, gv, pv, gref, pref, encP, encW,
                                       pre0, h0b, c0b, out_logits, out_ptrs);
}

// Round 11
// 6422.588 us; speedup vs baseline: 1.6678x; 1.6678x over previous
//
#include <hip/hip_runtime.h>
#include <cstdint>
#include <cstddef>

#define DEVINL __device__ __forceinline__

typedef float f32x4 __attribute__((ext_vector_type(4)));

DEVINL float ntload1(const float* p) {
    return __builtin_nontemporal_load(p);
}
DEVINL f32x4 ld4(const float* p) {
    return *reinterpret_cast<const f32x4*>(p);
}

// ---------- math helpers ----------
DEVINL float frcp(float x) { return __builtin_amdgcn_rcpf(x); }
DEVINL float ftanh_fast(float x) {
    float e = __expf(2.0f * x);
    return 1.0f - 2.0f * frcp(e + 1.0f);
}
DEVINL float sig_precise(float x) { return 1.0f / (1.0f + expf(-x)); }
DEVINL float tanh_precise(float x) { return tanhf(x); }

// ---------- sizes ----------
#define BB 128
#define SS 128
#define IND 16
#define DD 256
#define HH 256
#define H4 1024
#define H2 512

// =====================================================================
// K1: emb = LayerNorm(tanh(x @ proj_W.T + proj_b))   (one block per row)
// =====================================================================
__global__ __launch_bounds__(256) void k_proj_ln(
    const float* __restrict__ x, const float* __restrict__ projW,
    const float* __restrict__ projB, const float* __restrict__ ln_g,
    const float* __restrict__ ln_b, float* __restrict__ emb)
{
    __shared__ float Wl[256 * 17];
    __shared__ float xl[16];
    __shared__ float red[256];
    const int row = blockIdx.x;
    const int tid = threadIdx.x;
    for (int idx = tid; idx < 256 * 16; idx += 256) {
        int d = idx >> 4, i = idx & 15;
        Wl[d * 17 + i] = projW[idx];
    }
    if (tid < 16) xl[tid] = x[row * 16 + tid];
    __syncthreads();
    float acc = projB[tid];
#pragma unroll
    for (int i = 0; i < 16; ++i) acc = fmaf(Wl[tid * 17 + i], xl[i], acc);
    float v = tanh_precise(acc);
    red[tid] = v;
    __syncthreads();
    for (int s2 = 128; s2 > 0; s2 >>= 1) { if (tid < s2) red[tid] += red[tid + s2]; __syncthreads(); }
    float mean = red[0] * (1.0f / 256.0f);
    __syncthreads();
    float dlt = v - mean;
    red[tid] = dlt * dlt;
    __syncthreads();
    for (int s2 = 128; s2 > 0; s2 >>= 1) { if (tid < s2) red[tid] += red[tid + s2]; __syncthreads(); }
    float var = red[0] * (1.0f / 256.0f);
    float rs = 1.0f / sqrtf(var + 1e-5f);
    emb[(size_t)row * 256 + tid] = dlt * rs * ln_g[tid] + ln_b[tid];
}

// =====================================================================
// K2: generic fp32 GEMM-NT  C(MxN) = A(MxK,lda) * B(NxK)^T (+bias1+bias2)
// =====================================================================
__global__ __launch_bounds__(256) void k_gemm_nt(
    const float* __restrict__ A, int lda,
    const float* __restrict__ Bm,
    float* __restrict__ C,
    int M, int N, int K,
    const float* __restrict__ bias1, const float* __restrict__ bias2,
    int flags)
{
    __shared__ __align__(16) float As[16][132];
    __shared__ __align__(16) float Bs[16][132];
    const int tid = threadIdx.x;
    const int m0 = blockIdx.x * 128;
    const int n0 = blockIdx.y * 128;
    const int r = tid >> 1, half = tid & 1;
    const int tm = tid & 15, tn = tid >> 4;
    float acc[8][8];
#pragma unroll
    for (int i = 0; i < 8; ++i)
#pragma unroll
        for (int j = 0; j < 8; ++j) acc[i][j] = 0.0f;

    for (int k0 = 0; k0 < K; k0 += 16) {
        const float4* pa = reinterpret_cast<const float4*>(&A[(size_t)(m0 + r) * lda + k0 + half * 8]);
        float4 a0 = pa[0], a1 = pa[1];
        const float4* pb = reinterpret_cast<const float4*>(&Bm[(size_t)(n0 + r) * K + k0 + half * 8]);
        float4 b0 = pb[0], b1 = pb[1];
        __syncthreads();
        const int kb = half * 8;
        As[kb + 0][r] = a0.x; As[kb + 1][r] = a0.y; As[kb + 2][r] = a0.z; As[kb + 3][r] = a0.w;
        As[kb + 4][r] = a1.x; As[kb + 5][r] = a1.y; As[kb + 6][r] = a1.z; As[kb + 7][r] = a1.w;
        Bs[kb + 0][r] = b0.x; Bs[kb + 1][r] = b0.y; Bs[kb + 2][r] = b0.z; Bs[kb + 3][r] = b0.w;
        Bs[kb + 4][r] = b1.x; Bs[kb + 5][r] = b1.y; Bs[kb + 6][r] = b1.z; Bs[kb + 7][r] = b1.w;
        __syncthreads();
#pragma unroll
        for (int kk = 0; kk < 16; ++kk) {
            const float4 xa0 = *reinterpret_cast<const float4*>(&As[kk][tm * 8]);
            const float4 xa1 = *reinterpret_cast<const float4*>(&As[kk][tm * 8 + 4]);
            const float4 xb0 = *reinterpret_cast<const float4*>(&Bs[kk][tn * 8]);
            const float4 xb1 = *reinterpret_cast<const float4*>(&Bs[kk][tn * 8 + 4]);
            const float av[8] = {xa0.x, xa0.y, xa0.z, xa0.w, xa1.x, xa1.y, xa1.z, xa1.w};
            const float bv[8] = {xb0.x, xb0.y, xb0.z, xb0.w, xb1.x, xb1.y, xb1.z, xb1.w};
#pragma unroll
            for (int i = 0; i < 8; ++i)
#pragma unroll
                for (int j = 0; j < 8; ++j) acc[i][j] = fmaf(av[i], bv[j], acc[i][j]);
        }
    }
    const int nb = n0 + tn * 8;
    float bias[8];
#pragma unroll
    for (int j = 0; j < 8; ++j) {
        float bbv = 0.0f;
        if (bias1) bbv += bias1[nb + j];
        if (bias2) bbv += bias2[nb + j];
        bias[j] = bbv;
    }
#pragma unroll
    for (int i = 0; i < 8; ++i) {
        const size_t m = (size_t)(m0 + tm * 8 + i);
        float o[8];
#pragma unroll
        for (int j = 0; j < 8; ++j) {
            float vv = acc[i][j] + bias[j];
            if (flags & 1) vv = tanh_precise(vv);
            o[j] = vv;
        }
        float4* pc = reinterpret_cast<float4*>(&C[m * N + nb]);
        pc[0] = make_float4(o[0], o[1], o[2], o[3]);
        pc[1] = make_float4(o[4], o[5], o[6], o[7]);
    }
}

// =====================================================================
// K3: bidirectional LSTM (R9 version): 128 WGs, 512 threads, 2 batches/WG,
// compact dbuf W-pass.
// =====================================================================
__global__ __launch_bounds__(512, 2) void k_lstm(
    const float* __restrict__ Whh_f, const float* __restrict__ Whh_b,
    const float* __restrict__ xf, const float* __restrict__ xb,
    float* __restrict__ enc, float* __restrict__ hT, float* __restrict__ cT)
{
    const int wg = blockIdx.x;       // 0..127
    const int dir = wg >> 6;
    const int grp = wg & 63;
    const int bb0 = grp * 2;
    const float* W = dir ? Whh_b : Whh_f;
    const float* xin = dir ? xb : xf;
    const int tid = threadIdx.x;
    const int oct = tid & 7, jg = tid >> 3;   // jg 0..63
    const int gc = tid & 255, gb = tid >> 8;

    __shared__ __align__(16) float h_lds[2][256];
    __shared__ float pre_lds[2][1024];

    for (int i = tid; i < 2 * 256; i += 512) (&h_lds[0][0])[i] = 0.0f;
    float c_reg = 0.0f;
    __syncthreads();

    for (int t = 0; t < SS; ++t) {
        const int st = dir ? (SS - 1 - t) : t;
        float hreg[2][32];
#pragma unroll
        for (int bsel = 0; bsel < 2; ++bsel) {
#pragma unroll
            for (int i = 0; i < 8; ++i) {
                f32x4 v = ld4(&h_lds[bsel][i * 32 + oct * 4]);
                hreg[bsel][i * 4 + 0] = v.x; hreg[bsel][i * 4 + 1] = v.y;
                hreg[bsel][i * 4 + 2] = v.z; hreg[bsel][i * 4 + 3] = v.w;
            }
        }
        {
            f32x4 wA[8], wB[8];
            {
                const float* bp = &W[(size_t)jg * 256 + oct * 4];
#pragma unroll
                for (int i = 0; i < 8; ++i) wA[i] = ld4(bp + i * 32);
            }
            auto wstep = [&](f32x4 (&cur)[8], f32x4 (&nxt)[8], int q) {
                if (q < 15) {
                    const float* bp = &W[(size_t)((q + 1) * 64 + jg) * 256 + oct * 4];
#pragma unroll
                    for (int i = 0; i < 8; ++i) nxt[i] = ld4(bp + i * 32);
                }
                float a0 = 0.0f, a1 = 0.0f;
#pragma unroll
                for (int i = 0; i < 8; ++i) {
                    a0 = fmaf(cur[i].x, hreg[0][i * 4 + 0], a0);
                    a0 = fmaf(cur[i].y, hreg[0][i * 4 + 1], a0);
                    a0 = fmaf(cur[i].z, hreg[0][i * 4 + 2], a0);
                    a0 = fmaf(cur[i].w, hreg[0][i * 4 + 3], a0);
                    a1 = fmaf(cur[i].x, hreg[1][i * 4 + 0], a1);
                    a1 = fmaf(cur[i].y, hreg[1][i * 4 + 1], a1);
                    a1 = fmaf(cur[i].z, hreg[1][i * 4 + 2], a1);
                    a1 = fmaf(cur[i].w, hreg[1][i * 4 + 3], a1);
                }
                a0 += __shfl_xor(a0, 1); a0 += __shfl_xor(a0, 2); a0 += __shfl_xor(a0, 4);
                a1 += __shfl_xor(a1, 1); a1 += __shfl_xor(a1, 2); a1 += __shfl_xor(a1, 4);
                if (oct == 0) {
                    const int row = q * 64 + jg;
                    pre_lds[0][row] = a0; pre_lds[1][row] = a1;
                }
            };
#pragma unroll 1
            for (int q = 0; q < 16; q += 2) { wstep(wA, wB, q); wstep(wB, wA, q + 1); }
        }
        __syncthreads();
        {
            const float* xrow = &xin[((size_t)(bb0 + gb) * SS + st) * 1024];
            float pi = pre_lds[gb][gc]       + ntload1(&xrow[gc]);
            float pf = pre_lds[gb][256 + gc] + ntload1(&xrow[256 + gc]);
            float pg = pre_lds[gb][512 + gc] + ntload1(&xrow[512 + gc]);
            float po = pre_lds[gb][768 + gc] + ntload1(&xrow[768 + gc]);
            float ig = sig_precise(pi), fg = sig_precise(pf);
            float gg = tanh_precise(pg), og = sig_precise(po);
            float cn = fmaf(fg, c_reg, ig * gg);
            float hn = og * tanh_precise(cn);
            c_reg = cn;
            h_lds[gb][gc] = hn;
            enc[((size_t)(bb0 + gb) * SS + st) * 512 + dir * 256 + gc] = hn;
            if (t == SS - 1) {
                hT[(size_t)(bb0 + gb) * 512 + dir * 256 + gc] = hn;
                cT[(size_t)(bb0 + gb) * 512 + dir * 256 + gc] = cn;
            }
        }
        __syncthreads();
    }
}

// =====================================================================
// K5: pre0[b][j] = mean_s encW[b][s][j]
// =====================================================================
__global__ __launch_bounds__(256) void k_meanw(const float* __restrict__ encW, float* __restrict__ pre0)
{
    const int b = blockIdx.x;
    const int tid = threadIdx.x;
    const float4* base = reinterpret_cast<const float4*>(&encW[(size_t)b * SS * 1024]);
    float sx = 0.0f, sy = 0.0f, sz = 0.0f, sw = 0.0f;
    for (int s = 0; s < SS; ++s) {
        float4 v = base[s * 256 + tid];
        sx += v.x; sy += v.y; sz += v.z; sw += v.w;
    }
    float4* out = reinterpret_cast<float4*>(&pre0[(size_t)b * 1024]);
    out[tid] = make_float4(sx * (1.0f / 128.0f), sy * (1.0f / 128.0f), sz * (1.0f / 128.0f), sw * (1.0f / 128.0f));
}

// =====================================================================
// K6: pointer decoder: 128 WGs x 1 batch, 1024 threads (4 waves/SIMD).
// Per-wave critical path HALVED vs R9: phase1 = 8 q-rounds of 128 rows
// (jg 0..127), phase3 = 4 rounds, phases 4/7 = single round, phase6 =
// 16 waves x 8 rows. Compact dbuf lambdas keep the body I$-resident.
// =====================================================================
__global__ __launch_bounds__(1024) void k_decoder(
    const float* __restrict__ Whh_d,
    const float* __restrict__ gW2, const float* __restrict__ pW2,
    const float* __restrict__ gv, const float* __restrict__ pv,
    const float* __restrict__ g_ref, const float* __restrict__ p_ref,
    const float* __restrict__ encP, const float* __restrict__ encW,
    const float* __restrict__ pre0, const float* __restrict__ h0,
    const float* __restrict__ c0,
    float* __restrict__ out_logits, float* __restrict__ out_ptrs)
{
    const int b = blockIdx.x;             // batch
    const int tid = threadIdx.x;
    const int oct = tid & 7, jg = tid >> 3;   // jg 0..127
    const int wid = tid >> 6, lane = tid & 63;

    __shared__ __align__(16) float h_lds[256];
    __shared__ float c_lds[256];
    __shared__ float pre_lds[1024];
    __shared__ float row_lds[1024];
    __shared__ __align__(16) float hgp[512];   // [0..255]=hg, [256..511]=hp1
    __shared__ __align__(16) float hp_lds[256];
    __shared__ __align__(16) float gv_lds[256];
    __shared__ __align__(16) float pv_lds[256];
    __shared__ float sc_arr[128];
    __shared__ float e_arr[128];
    __shared__ __align__(16) float hp_half[16][256];
    __shared__ int mask_lds[128];
    __shared__ float Z_s;
    __shared__ int sel_s;

    if (tid < 256) {
        gv_lds[tid] = gv[tid];
        pv_lds[tid] = pv[tid];
        h_lds[tid] = h0[(size_t)b * 256 + tid];
        c_lds[tid] = c0[(size_t)b * 256 + tid];
    }
    if (tid < 128) mask_lds[tid] = 0;
    if (tid == 0) sel_s = -1;
    const float* grefb = g_ref + (size_t)b * SS * 256;
    const float* prefb = p_ref + (size_t)b * SS * 256;
    const float* encPb = encP + (size_t)b * SS * 256;
    __syncthreads();

    for (int t = 0; t < SS; ++t) {
        // ---- stage xt row (encW[sel] or pre0); h_{t-1} -> regs ----
        {
            const int sel = sel_s;
            const float* src = (sel < 0) ? &pre0[(size_t)b * 1024]
                                         : &encW[((size_t)(b * SS + sel)) * 1024];
            row_lds[tid] = src[tid];
        }
        float hreg[32];
#pragma unroll
        for (int i = 0; i < 8; ++i) {
            f32x4 v = ld4(&h_lds[i * 32 + oct * 4]);
            hreg[i * 4 + 0] = v.x; hreg[i * 4 + 1] = v.y;
            hreg[i * 4 + 2] = v.z; hreg[i * 4 + 3] = v.w;
        }
        __syncthreads();
        // ---- phase 1: pre = row + Whh_d @ h (8 rounds of 128 rows, dbuf) ----
        {
            f32x4 wA[8], wB[8];
            {
                const float* bp = &Whh_d[(size_t)jg * 256 + oct * 4];
#pragma unroll
                for (int i = 0; i < 8; ++i) wA[i] = ld4(bp + i * 32);
            }
            auto p1 = [&](f32x4 (&cur)[8], f32x4 (&nxt)[8], int q) {
                if (q < 7) {
                    const float* bp = &Whh_d[(size_t)((q + 1) * 128 + jg) * 256 + oct * 4];
#pragma unroll
                    for (int i = 0; i < 8; ++i) nxt[i] = ld4(bp + i * 32);
                }
                float a0 = 0.0f;
#pragma unroll
                for (int i = 0; i < 8; ++i) {
                    a0 = fmaf(cur[i].x, hreg[i * 4 + 0], a0);
                    a0 = fmaf(cur[i].y, hreg[i * 4 + 1], a0);
                    a0 = fmaf(cur[i].z, hreg[i * 4 + 2], a0);
                    a0 = fmaf(cur[i].w, hreg[i * 4 + 3], a0);
                }
                a0 += __shfl_xor(a0, 1); a0 += __shfl_xor(a0, 2); a0 += __shfl_xor(a0, 4);
                if (oct == 0) {
                    const int row = q * 128 + jg;
                    pre_lds[row] = a0 + row_lds[row];
                }
            };
#pragma unroll 1
            for (int q = 0; q < 8; q += 2) { p1(wA, wB, q); p1(wB, wA, q + 1); }
        }
        __syncthreads();
        // ---- phase 2: gates ----
        if (tid < 256) {
            const int ch = tid;
            float pi = pre_lds[ch],        pf = pre_lds[256 + ch];
            float pg = pre_lds[512 + ch],  po = pre_lds[768 + ch];
            float ig = sig_precise(pi), fg = sig_precise(pf);
            float gg = tanh_precise(pg), og = sig_precise(po);
            float cn = fmaf(fg, c_lds[ch], ig * gg);
            float hn = og * tanh_precise(cn);
            c_lds[ch] = cn;
            h_lds[ch] = hn;
        }
        __syncthreads();
        // reload new h slice
        float hreg2[32];
#pragma unroll
        for (int i = 0; i < 8; ++i) {
            f32x4 v = ld4(&h_lds[i * 32 + oct * 4]);
            hreg2[i * 4 + 0] = v.x; hreg2[i * 4 + 1] = v.y;
            hreg2[i * 4 + 2] = v.z; hreg2[i * 4 + 3] = v.w;
        }
        // ---- phase 3: hg (rows 0..255) / hp1 (rows 256..511), 4 rounds ----
        {
            f32x4 wA[8], wB[8];
            {
                const float* src0 = (jg < 256) ? &gW2[(size_t)jg * 256] : &pW2[(size_t)(jg - 256) * 256];
#pragma unroll
                for (int i = 0; i < 8; ++i) wA[i] = ld4(src0 + oct * 4 + i * 32);
            }
            auto p3 = [&](f32x4 (&cur)[8], f32x4 (&nxt)[8], int q) {
                if (q < 3) {
                    const int r2 = (q + 1) * 128 + jg;
                    const float* src = (r2 < 256) ? &gW2[(size_t)r2 * 256] : &pW2[(size_t)(r2 - 256) * 256];
#pragma unroll
                    for (int i = 0; i < 8; ++i) nxt[i] = ld4(src + oct * 4 + i * 32);
                }
                float a0 = 0.0f;
#pragma unroll
                for (int i = 0; i < 8; ++i) {
                    a0 = fmaf(cur[i].x, hreg2[i * 4 + 0], a0);
                    a0 = fmaf(cur[i].y, hreg2[i * 4 + 1], a0);
                    a0 = fmaf(cur[i].z, hreg2[i * 4 + 2], a0);
                    a0 = fmaf(cur[i].w, hreg2[i * 4 + 3], a0);
                }
                a0 += __shfl_xor(a0, 1); a0 += __shfl_xor(a0, 2); a0 += __shfl_xor(a0, 4);
                if (oct == 0) hgp[q * 128 + jg] = a0;
            };
#pragma unroll 1
            for (int q = 0; q < 4; q += 2) { p3(wA, wB, q); p3(wB, wA, q + 1); }
        }
        __syncthreads();
        // ---- phase 4: gs scores (each jg-group: one row) ----
        {
            const float* gr = &grefb[(size_t)jg * 256 + oct * 4];
            f32x4 g0[8];
#pragma unroll
            for (int i = 0; i < 8; ++i) g0[i] = ld4(gr + i * 32);
            float part = 0.0f;
#pragma unroll
            for (int i = 0; i < 8; ++i) {
                const int d = i * 32 + oct * 4;
                const f32x4 hh = ld4(&hgp[d]);
                const f32x4 vv = ld4(&gv_lds[d]);
                part = fmaf(ftanh_fast(g0[i].x + hh.x), vv.x, part);
                part = fmaf(ftanh_fast(g0[i].y + hh.y), vv.y, part);
                part = fmaf(ftanh_fast(g0[i].z + hh.z), vv.z, part);
                part = fmaf(ftanh_fast(g0[i].w + hh.w), vv.w, part);
            }
            part += __shfl_xor(part, 1); part += __shfl_xor(part, 2); part += __shfl_xor(part, 4);
            if (oct == 0) sc_arr[jg] = mask_lds[jg] ? -1e9f : part * 0.0625f;
        }
        __syncthreads();
        // ---- phase 5: softmax (wave 0) ----
        if (tid < 64) {
            float s0 = sc_arr[lane], s1 = sc_arr[lane + 64];
            float m = fmaxf(s0, s1);
#pragma unroll
            for (int mk = 1; mk < 64; mk <<= 1) m = fmaxf(m, __shfl_xor(m, mk));
            float e0 = expf(s0 - m), e1 = expf(s1 - m);
            e_arr[lane] = e0; e_arr[lane + 64] = e1;
            float z = e0 + e1;
#pragma unroll
            for (int mk = 1; mk < 64; mk <<= 1) z += __shfl_xor(z, mk);
            if (lane == 0) Z_s = z;
        }
        __syncthreads();
        // ---- phase 6: ctx partials (16 waves x 8 s-rows, branchless) ----
        {
            const int d4 = lane * 4;
            const float* base6 = &encPb[((size_t)(wid * 8)) * 256 + d4];
            f32x4 p0[8];
#pragma unroll
            for (int i = 0; i < 8; ++i) p0[i] = ld4(base6 + i * 256);
            float ax = 0.0f, ay = 0.0f, az = 0.0f, aw = 0.0f;
#pragma unroll
            for (int i = 0; i < 8; ++i) {
                const float e = e_arr[wid * 8 + i];
                ax = fmaf(p0[i].x, e, ax); ay = fmaf(p0[i].y, e, ay);
                az = fmaf(p0[i].z, e, az); aw = fmaf(p0[i].w, e, aw);
            }
            *reinterpret_cast<float4*>(&hp_half[wid][d4]) = make_float4(ax, ay, az, aw);
        }
        __syncthreads();
        if (tid < 256) {
            float s = 0.0f;
#pragma unroll
            for (int k = 0; k < 16; ++k) s += hp_half[k][tid];
            hp_lds[tid] = hgp[256 + tid] + s * frcp(Z_s);
        }
        __syncthreads();
        // ---- phase 7: ps scores (each jg-group: one row) ----
        {
            const float* pr = &prefb[(size_t)jg * 256 + oct * 4];
            f32x4 g0[8];
#pragma unroll
            for (int i = 0; i < 8; ++i) g0[i] = ld4(pr + i * 32);
            float part = 0.0f;
#pragma unroll
            for (int i = 0; i < 8; ++i) {
                const int d = i * 32 + oct * 4;
                const f32x4 hh = ld4(&hp_lds[d]);
                const f32x4 vv = ld4(&pv_lds[d]);
                part = fmaf(ftanh_fast(g0[i].x + hh.x), vv.x, part);
                part = fmaf(ftanh_fast(g0[i].y + hh.y), vv.y, part);
                part = fmaf(ftanh_fast(g0[i].z + hh.z), vv.z, part);
                part = fmaf(ftanh_fast(g0[i].w + hh.w), vv.w, part);
            }
            part += __shfl_xor(part, 1); part += __shfl_xor(part, 2); part += __shfl_xor(part, 4);
            if (oct == 0) sc_arr[jg] = mask_lds[jg] ? -1e9f : part * 0.0625f;
        }
        __syncthreads();
        // ---- phase 8: logits write + argmax (first-max semantics) ----
        if (tid < 128) {
            out_logits[((size_t)(b * SS + t)) * SS + tid] = sc_arr[tid];
        }
        if (tid < 64) {
            float v = sc_arr[lane];
            int idx = lane;
            float v2 = sc_arr[lane + 64];
            if (v2 > v) { v = v2; idx = lane + 64; }
#pragma unroll
            for (int mk = 1; mk < 64; mk <<= 1) {
                float ov = __shfl_xor(v, mk);
                int oi = __shfl_xor(idx, mk);
                if (ov > v || (ov == v && oi < idx)) { v = ov; idx = oi; }
            }
            if (lane == 0) {
                sel_s = idx;
                mask_lds[idx] = 1;
                out_ptrs[(size_t)b * SS + t] = (float)idx;
            }
        }
        __syncthreads();
    }
}

// =====================================================================
// host launcher
// =====================================================================
extern "C" void kernel_launch(void* const* d_in, const int* in_sizes, int n_in,
                              void* d_out, int out_size, void* d_ws, size_t ws_size,
                              hipStream_t stream)
{
    (void)in_sizes; (void)n_in; (void)out_size; (void)ws_size;
    const float* x      = (const float*)d_in[0];
    const float* proj_W = (const float*)d_in[1];
    const float* proj_b = (const float*)d_in[2];
    const float* ln_g   = (const float*)d_in[3];
    const float* ln_b   = (const float*)d_in[4];
    const float* Wih_f  = (const float*)d_in[5];
    const float* Whh_f  = (const float*)d_in[6];
    const float* bih_f  = (const float*)d_in[7];
    const float* bhh_f  = (const float*)d_in[8];
    const float* Wih_b  = (const float*)d_in[9];
    const float* Whh_b  = (const float*)d_in[10];
    const float* bih_b  = (const float*)d_in[11];
    const float* bhh_b  = (const float*)d_in[12];
    const float* Wih_d  = (const float*)d_in[13];
    const float* Whh_d  = (const float*)d_in[14];
    const float* bih_d  = (const float*)d_in[15];
    const float* bhh_d  = (const float*)d_in[16];
    const float* hb_W   = (const float*)d_in[17];
    const float* hb_b   = (const float*)d_in[18];
    const float* cb_W   = (const float*)d_in[19];
    const float* cb_b   = (const float*)d_in[20];
    const float* gW1    = (const float*)d_in[21];
    const float* gW2    = (const float*)d_in[22];
    const float* gv     = (const float*)d_in[23];
    const float* pW1    = (const float*)d_in[24];
    const float* pW2    = (const float*)d_in[25];
    const float* pv     = (const float*)d_in[26];

    float* ws = (float*)d_ws;
    const size_t o_hT    = 0;
    const size_t o_cT    = 65536;
    const size_t o_h0    = 131072;
    const size_t o_c0    = 163840;
    const size_t o_pre0  = 196608;
    const size_t o_emb   = 0;
    const size_t o_xf    = 4194304;
    const size_t o_xb    = o_xf + 16777216;
    const size_t o_enc   = o_xb + 16777216;
    const size_t o_encW  = o_xf;
    const size_t o_gref  = o_xb;
    const size_t o_pref  = o_xb + 4194304;
    const size_t o_encP  = o_xb + 8388608;

    float* emb  = ws + o_emb;
    float* xf   = ws + o_xf;
    float* xb   = ws + o_xb;
    float* enc  = ws + o_enc;
    float* hT   = ws + o_hT;
    float* cT   = ws + o_cT;
    float* h0b  = ws + o_h0;
    float* c0b  = ws + o_c0;
    float* pre0 = ws + o_pre0;
    float* encW = ws + o_encW;
    float* gref = ws + o_gref;
    float* pref = ws + o_pref;
    float* encP = ws + o_encP;

    float* out_logits = (float*)d_out;
    float* out_ptrs   = out_logits + (size_t)BB * SS * SS;

    // 1. emb
    k_proj_ln<<<BB * SS, 256, 0, stream>>>(x, proj_W, proj_b, ln_g, ln_b, emb);
    // 2-3. xf / xb  (bias = bih + bhh)
    {
        dim3 g(128, 8);
        k_gemm_nt<<<g, 256, 0, stream>>>(emb, 256, Wih_f, xf, 16384, 1024, 256, bih_f, bhh_f, 0);
        k_gemm_nt<<<g, 256, 0, stream>>>(emb, 256, Wih_b, xb, 16384, 1024, 256, bih_b, bhh_b, 0);
    }
    // 4. LSTM both directions (R9 proven version)
    k_lstm<<<128, 512, 0, stream>>>(Whh_f, Whh_b, xf, xb, enc, hT, cT);
    // 5-6. h0 / c0
    {
        dim3 g(1, 2);
        k_gemm_nt<<<g, 256, 0, stream>>>(hT, 512, hb_W, h0b, 128, 256, 512, hb_b, nullptr, 1);
        k_gemm_nt<<<g, 256, 0, stream>>>(cT, 512, cb_W, c0b, 128, 256, 512, cb_b, nullptr, 1);
    }
    // 7-10. attention precomputes
    {
        dim3 g2(128, 2);
        k_gemm_nt<<<g2, 256, 0, stream>>>(enc, 512, gW1, gref, 16384, 256, 512, nullptr, nullptr, 0);
        k_gemm_nt<<<g2, 256, 0, stream>>>(enc, 512, pW1, pref, 16384, 256, 512, nullptr, nullptr, 0);
        dim3 g1(128, 8);
        k_gemm_nt<<<g1, 256, 0, stream>>>(enc, 512, Wih_d, encW, 16384, 1024, 512, bih_d, bhh_d, 0);
        k_gemm_nt<<<g2, 256, 0, stream>>>(enc, 512, pW2, encP, 16384, 256, 256, nullptr, nullptr, 0);
    }
    // 11. pre0 = mean_s encW
    k_meanw<<<BB, 256, 0, stream>>>(encW, pre0);
    // 12. decoder: 128 WGs x 1 batch x 1024 threads (halved per-wave path)
    k_decoder<<<128, 1024, 0, stream>>>(Whh_d, gW2, pW2, gv, pv, gref, pref, encP, encW,
                                        pre0, h0b, c0b, out_logits, out_ptrs);
}

// Round 12
// 5915.620 us; speedup vs baseline: 1.8107x; 1.0857x over previous
//
#include <hip/hip_runtime.h>
#include <cstdint>
#include <cstddef>

#define DEVINL __device__ __forceinline__

typedef float f32x4 __attribute__((ext_vector_type(4)));

DEVINL float ntload1(const float* p) {
    return __builtin_nontemporal_load(p);
}
DEVINL f32x4 ld4(const float* p) {
    return *reinterpret_cast<const f32x4*>(p);
}

// ---------- math helpers ----------
DEVINL float frcp(float x) { return __builtin_amdgcn_rcpf(x); }
DEVINL float ftanh_fast(float x) {
    float e = __expf(2.0f * x);
    return 1.0f - 2.0f * frcp(e + 1.0f);
}
DEVINL float sig_precise(float x) { return 1.0f / (1.0f + expf(-x)); }
DEVINL float tanh_precise(float x) { return tanhf(x); }

// ---------- sizes ----------
#define BB 128
#define SS 128
#define IND 16
#define DD 256
#define HH 256
#define H4 1024
#define H2 512

// =====================================================================
// K1: emb = LayerNorm(tanh(x @ proj_W.T + proj_b))   (one block per row)
// =====================================================================
__global__ __launch_bounds__(256) void k_proj_ln(
    const float* __restrict__ x, const float* __restrict__ projW,
    const float* __restrict__ projB, const float* __restrict__ ln_g,
    const float* __restrict__ ln_b, float* __restrict__ emb)
{
    __shared__ float Wl[256 * 17];
    __shared__ float xl[16];
    __shared__ float red[256];
    const int row = blockIdx.x;
    const int tid = threadIdx.x;
    for (int idx = tid; idx < 256 * 16; idx += 256) {
        int d = idx >> 4, i = idx & 15;
        Wl[d * 17 + i] = projW[idx];
    }
    if (tid < 16) xl[tid] = x[row * 16 + tid];
    __syncthreads();
    float acc = projB[tid];
#pragma unroll
    for (int i = 0; i < 16; ++i) acc = fmaf(Wl[tid * 17 + i], xl[i], acc);
    float v = tanh_precise(acc);
    red[tid] = v;
    __syncthreads();
    for (int s2 = 128; s2 > 0; s2 >>= 1) { if (tid < s2) red[tid] += red[tid + s2]; __syncthreads(); }
    float mean = red[0] * (1.0f / 256.0f);
    __syncthreads();
    float dlt = v - mean;
    red[tid] = dlt * dlt;
    __syncthreads();
    for (int s2 = 128; s2 > 0; s2 >>= 1) { if (tid < s2) red[tid] += red[tid + s2]; __syncthreads(); }
    float var = red[0] * (1.0f / 256.0f);
    float rs = 1.0f / sqrtf(var + 1e-5f);
    emb[(size_t)row * 256 + tid] = dlt * rs * ln_g[tid] + ln_b[tid];
}

// =====================================================================
// K2: generic fp32 GEMM-NT  C(MxN) = A(MxK,lda) * B(NxK)^T (+bias1+bias2)
// =====================================================================
__global__ __launch_bounds__(256) void k_gemm_nt(
    const float* __restrict__ A, int lda,
    const float* __restrict__ Bm,
    float* __restrict__ C,
    int M, int N, int K,
    const float* __restrict__ bias1, const float* __restrict__ bias2,
    int flags)
{
    __shared__ __align__(16) float As[16][132];
    __shared__ __align__(16) float Bs[16][132];
    const int tid = threadIdx.x;
    const int m0 = blockIdx.x * 128;
    const int n0 = blockIdx.y * 128;
    const int r = tid >> 1, half = tid & 1;
    const int tm = tid & 15, tn = tid >> 4;
    float acc[8][8];
#pragma unroll
    for (int i = 0; i < 8; ++i)
#pragma unroll
        for (int j = 0; j < 8; ++j) acc[i][j] = 0.0f;

    for (int k0 = 0; k0 < K; k0 += 16) {
        const float4* pa = reinterpret_cast<const float4*>(&A[(size_t)(m0 + r) * lda + k0 + half * 8]);
        float4 a0 = pa[0], a1 = pa[1];
        const float4* pb = reinterpret_cast<const float4*>(&Bm[(size_t)(n0 + r) * K + k0 + half * 8]);
        float4 b0 = pb[0], b1 = pb[1];
        __syncthreads();
        const int kb = half * 8;
        As[kb + 0][r] = a0.x; As[kb + 1][r] = a0.y; As[kb + 2][r] = a0.z; As[kb + 3][r] = a0.w;
        As[kb + 4][r] = a1.x; As[kb + 5][r] = a1.y; As[kb + 6][r] = a1.z; As[kb + 7][r] = a1.w;
        Bs[kb + 0][r] = b0.x; Bs[kb + 1][r] = b0.y; Bs[kb + 2][r] = b0.z; Bs[kb + 3][r] = b0.w;
        Bs[kb + 4][r] = b1.x; Bs[kb + 5][r] = b1.y; Bs[kb + 6][r] = b1.z; Bs[kb + 7][r] = b1.w;
        __syncthreads();
#pragma unroll
        for (int kk = 0; kk < 16; ++kk) {
            const float4 xa0 = *reinterpret_cast<const float4*>(&As[kk][tm * 8]);
            const float4 xa1 = *reinterpret_cast<const float4*>(&As[kk][tm * 8 + 4]);
            const float4 xb0 = *reinterpret_cast<const float4*>(&Bs[kk][tn * 8]);
            const float4 xb1 = *reinterpret_cast<const float4*>(&Bs[kk][tn * 8 + 4]);
            const float av[8] = {xa0.x, xa0.y, xa0.z, xa0.w, xa1.x, xa1.y, xa1.z, xa1.w};
            const float bv[8] = {xb0.x, xb0.y, xb0.z, xb0.w, xb1.x, xb1.y, xb1.z, xb1.w};
#pragma unroll
            for (int i = 0; i < 8; ++i)
#pragma unroll
                for (int j = 0; j < 8; ++j) acc[i][j] = fmaf(av[i], bv[j], acc[i][j]);
        }
    }
    const int nb = n0 + tn * 8;
    float bias[8];
#pragma unroll
    for (int j = 0; j < 8; ++j) {
        float bbv = 0.0f;
        if (bias1) bbv += bias1[nb + j];
        if (bias2) bbv += bias2[nb + j];
        bias[j] = bbv;
    }
#pragma unroll
    for (int i = 0; i < 8; ++i) {
        const size_t m = (size_t)(m0 + tm * 8 + i);
        float o[8];
#pragma unroll
        for (int j = 0; j < 8; ++j) {
            float vv = acc[i][j] + bias[j];
            if (flags & 1) vv = tanh_precise(vv);
            o[j] = vv;
        }
        float4* pc = reinterpret_cast<float4*>(&C[m * N + nb]);
        pc[0] = make_float4(o[0], o[1], o[2], o[3]);
        pc[1] = make_float4(o[4], o[5], o[6], o[7]);
    }
}

// =====================================================================
// K3: bidirectional LSTM: 256 WGs x 512 threads, ONE (batch,dir) chain
// per WG -> all 256 CUs busy. Compact dbuf W-pass (16 rounds of 64 rows).
// =====================================================================
__global__ __launch_bounds__(512, 2) void k_lstm(
    const float* __restrict__ Whh_f, const float* __restrict__ Whh_b,
    const float* __restrict__ xf, const float* __restrict__ xb,
    float* __restrict__ enc, float* __restrict__ hT, float* __restrict__ cT)
{
    const int wg = blockIdx.x;       // 0..255
    const int dir = wg >> 7;
    const int bat = wg & 127;
    const float* W = dir ? Whh_b : Whh_f;
    const float* xin = dir ? xb : xf;
    const int tid = threadIdx.x;
    const int oct = tid & 7, jg = tid >> 3;   // jg 0..63

    __shared__ __align__(16) float h_lds[256];
    __shared__ float pre_lds[1024];

    if (tid < 256) h_lds[tid] = 0.0f;
    float c_reg = 0.0f;
    __syncthreads();

    for (int t = 0; t < SS; ++t) {
        const int st = dir ? (SS - 1 - t) : t;
        float hreg[32];
#pragma unroll
        for (int i = 0; i < 8; ++i) {
            f32x4 v = ld4(&h_lds[i * 32 + oct * 4]);
            hreg[i * 4 + 0] = v.x; hreg[i * 4 + 1] = v.y;
            hreg[i * 4 + 2] = v.z; hreg[i * 4 + 3] = v.w;
        }
        {
            f32x4 wA[8], wB[8];
            {
                const float* bp = &W[(size_t)jg * 256 + oct * 4];
#pragma unroll
                for (int i = 0; i < 8; ++i) wA[i] = ld4(bp + i * 32);
            }
            auto wstep = [&](f32x4 (&cur)[8], f32x4 (&nxt)[8], int q) {
                if (q < 15) {
                    const float* bp = &W[(size_t)((q + 1) * 64 + jg) * 256 + oct * 4];
#pragma unroll
                    for (int i = 0; i < 8; ++i) nxt[i] = ld4(bp + i * 32);
                }
                float a0 = 0.0f;
#pragma unroll
                for (int i = 0; i < 8; ++i) {
                    a0 = fmaf(cur[i].x, hreg[i * 4 + 0], a0);
                    a0 = fmaf(cur[i].y, hreg[i * 4 + 1], a0);
                    a0 = fmaf(cur[i].z, hreg[i * 4 + 2], a0);
                    a0 = fmaf(cur[i].w, hreg[i * 4 + 3], a0);
                }
                a0 += __shfl_xor(a0, 1); a0 += __shfl_xor(a0, 2); a0 += __shfl_xor(a0, 4);
                if (oct == 0) pre_lds[q * 64 + jg] = a0;
            };
#pragma unroll 1
            for (int q = 0; q < 16; q += 2) { wstep(wA, wB, q); wstep(wB, wA, q + 1); }
        }
        __syncthreads();
        if (tid < 256) {
            const int gc = tid;
            const float* xrow = &xin[((size_t)bat * SS + st) * 1024];
            float pi = pre_lds[gc]       + ntload1(&xrow[gc]);
            float pf = pre_lds[256 + gc] + ntload1(&xrow[256 + gc]);
            float pg = pre_lds[512 + gc] + ntload1(&xrow[512 + gc]);
            float po = pre_lds[768 + gc] + ntload1(&xrow[768 + gc]);
            float ig = sig_precise(pi), fg = sig_precise(pf);
            float gg = tanh_precise(pg), og = sig_precise(po);
            float cn = fmaf(fg, c_reg, ig * gg);
            float hn = og * tanh_precise(cn);
            c_reg = cn;
            h_lds[gc] = hn;
            enc[((size_t)bat * SS + st) * 512 + dir * 256 + gc] = hn;
            if (t == SS - 1) {
                hT[(size_t)bat * 512 + dir * 256 + gc] = hn;
                cT[(size_t)bat * 512 + dir * 256 + gc] = cn;
            }
        }
        __syncthreads();
    }
}

// =====================================================================
// K5: pre0[b][j] = mean_s encW[b][s][j]
// =====================================================================
__global__ __launch_bounds__(256) void k_meanw(const float* __restrict__ encW, float* __restrict__ pre0)
{
    const int b = blockIdx.x;
    const int tid = threadIdx.x;
    const float4* base = reinterpret_cast<const float4*>(&encW[(size_t)b * SS * 1024]);
    float sx = 0.0f, sy = 0.0f, sz = 0.0f, sw = 0.0f;
    for (int s = 0; s < SS; ++s) {
        float4 v = base[s * 256 + tid];
        sx += v.x; sy += v.y; sz += v.z; sw += v.w;
    }
    float4* out = reinterpret_cast<float4*>(&pre0[(size_t)b * 1024]);
    out[tid] = make_float4(sx * (1.0f / 128.0f), sy * (1.0f / 128.0f), sz * (1.0f / 128.0f), sw * (1.0f / 128.0f));
}

// =====================================================================
// K6: pointer decoder: 128 WGs x 1 batch, 1024 threads (4 waves/SIMD).
// R11 structure + MASK COMPACTION: per step build the list of unmasked
// rows (one-wave ballot scan); phases 4/6/7 touch only the 128-t live
// rows (masked rows contribute e=0 / -1e9 exactly as before). Halves
// the L2-miss ref traffic that R11 showed to be the bound.
// =====================================================================
__global__ __launch_bounds__(1024) void k_decoder(
    const float* __restrict__ Whh_d,
    const float* __restrict__ gW2, const float* __restrict__ pW2,
    const float* __restrict__ gv, const float* __restrict__ pv,
    const float* __restrict__ g_ref, const float* __restrict__ p_ref,
    const float* __restrict__ encP, const float* __restrict__ encW,
    const float* __restrict__ pre0, const float* __restrict__ h0,
    const float* __restrict__ c0,
    float* __restrict__ out_logits, float* __restrict__ out_ptrs)
{
    const int b = blockIdx.x;             // batch
    const int tid = threadIdx.x;
    const int oct = tid & 7, jg = tid >> 3;   // jg 0..127
    const int wid = tid >> 6, lane = tid & 63;

    __shared__ __align__(16) float h_lds[256];
    __shared__ float c_lds[256];
    __shared__ float pre_lds[1024];
    __shared__ float row_lds[1024];
    __shared__ __align__(16) float hgp[512];   // [0..255]=hg, [256..511]=hp1
    __shared__ __align__(16) float hp_lds[256];
    __shared__ __align__(16) float gv_lds[256];
    __shared__ __align__(16) float pv_lds[256];
    __shared__ float sc_arr[128];
    __shared__ float e_arr[128];
    __shared__ __align__(16) float hp_half[16][256];
    __shared__ int mask_lds[128];
    __shared__ int ulist[128];
    __shared__ int ucount_s;
    __shared__ float Z_s;
    __shared__ int sel_s;

    if (tid < 256) {
        gv_lds[tid] = gv[tid];
        pv_lds[tid] = pv[tid];
        h_lds[tid] = h0[(size_t)b * 256 + tid];
        c_lds[tid] = c0[(size_t)b * 256 + tid];
    }
    if (tid < 128) mask_lds[tid] = 0;
    if (tid == 0) sel_s = -1;
    const float* grefb = g_ref + (size_t)b * SS * 256;
    const float* prefb = p_ref + (size_t)b * SS * 256;
    const float* encPb = encP + (size_t)b * SS * 256;
    __syncthreads();

    for (int t = 0; t < SS; ++t) {
        // ---- stage xt row; init sc=-1e9; build compacted unmasked list ----
        {
            const int sel = sel_s;
            const float* src = (sel < 0) ? &pre0[(size_t)b * 1024]
                                         : &encW[((size_t)(b * SS + sel)) * 1024];
            row_lds[tid] = src[tid];
        }
        if (tid >= 128 && tid < 256) sc_arr[tid - 128] = -1e9f;
        if (tid < 64) {
            const unsigned long long lowmask = (1ull << lane) - 1ull;
            const bool u0 = (mask_lds[lane] == 0);
            const unsigned long long b0m = __ballot(u0);
            if (u0) ulist[__popcll(b0m & lowmask)] = lane;
            const bool u1 = (mask_lds[lane + 64] == 0);
            const unsigned long long b1m = __ballot(u1);
            const int c0 = __popcll(b0m);
            if (u1) ulist[c0 + __popcll(b1m & lowmask)] = lane + 64;
            if (lane == 0) ucount_s = c0 + __popcll(b1m);
        }
        float hreg[32];
#pragma unroll
        for (int i = 0; i < 8; ++i) {
            f32x4 v = ld4(&h_lds[i * 32 + oct * 4]);
            hreg[i * 4 + 0] = v.x; hreg[i * 4 + 1] = v.y;
            hreg[i * 4 + 2] = v.z; hreg[i * 4 + 3] = v.w;
        }
        __syncthreads();
        // ---- phase 1: pre = row + Whh_d @ h (8 rounds of 128 rows, dbuf) ----
        {
            f32x4 wA[8], wB[8];
            {
                const float* bp = &Whh_d[(size_t)jg * 256 + oct * 4];
#pragma unroll
                for (int i = 0; i < 8; ++i) wA[i] = ld4(bp + i * 32);
            }
            auto p1 = [&](f32x4 (&cur)[8], f32x4 (&nxt)[8], int q) {
                if (q < 7) {
                    const float* bp = &Whh_d[(size_t)((q + 1) * 128 + jg) * 256 + oct * 4];
#pragma unroll
                    for (int i = 0; i < 8; ++i) nxt[i] = ld4(bp + i * 32);
                }
                float a0 = 0.0f;
#pragma unroll
                for (int i = 0; i < 8; ++i) {
                    a0 = fmaf(cur[i].x, hreg[i * 4 + 0], a0);
                    a0 = fmaf(cur[i].y, hreg[i * 4 + 1], a0);
                    a0 = fmaf(cur[i].z, hreg[i * 4 + 2], a0);
                    a0 = fmaf(cur[i].w, hreg[i * 4 + 3], a0);
                }
                a0 += __shfl_xor(a0, 1); a0 += __shfl_xor(a0, 2); a0 += __shfl_xor(a0, 4);
                if (oct == 0) {
                    const int row = q * 128 + jg;
                    pre_lds[row] = a0 + row_lds[row];
                }
            };
#pragma unroll 1
            for (int q = 0; q < 8; q += 2) { p1(wA, wB, q); p1(wB, wA, q + 1); }
        }
        __syncthreads();
        // ---- phase 2: gates ----
        if (tid < 256) {
            const int ch = tid;
            float pi = pre_lds[ch],        pf = pre_lds[256 + ch];
            float pg = pre_lds[512 + ch],  po = pre_lds[768 + ch];
            float ig = sig_precise(pi), fg = sig_precise(pf);
            float gg = tanh_precise(pg), og = sig_precise(po);
            float cn = fmaf(fg, c_lds[ch], ig * gg);
            float hn = og * tanh_precise(cn);
            c_lds[ch] = cn;
            h_lds[ch] = hn;
        }
        __syncthreads();
        // reload new h slice
        float hreg2[32];
#pragma unroll
        for (int i = 0; i < 8; ++i) {
            f32x4 v = ld4(&h_lds[i * 32 + oct * 4]);
            hreg2[i * 4 + 0] = v.x; hreg2[i * 4 + 1] = v.y;
            hreg2[i * 4 + 2] = v.z; hreg2[i * 4 + 3] = v.w;
        }
        // ---- phase 3: hg (rows 0..255) / hp1 (rows 256..511), 4 rounds ----
        {
            f32x4 wA[8], wB[8];
            {
                const float* src0 = (jg < 256) ? &gW2[(size_t)jg * 256] : &pW2[(size_t)(jg - 256) * 256];
#pragma unroll
                for (int i = 0; i < 8; ++i) wA[i] = ld4(src0 + oct * 4 + i * 32);
            }
            auto p3 = [&](f32x4 (&cur)[8], f32x4 (&nxt)[8], int q) {
                if (q < 3) {
                    const int r2 = (q + 1) * 128 + jg;
                    const float* src = (r2 < 256) ? &gW2[(size_t)r2 * 256] : &pW2[(size_t)(r2 - 256) * 256];
#pragma unroll
                    for (int i = 0; i < 8; ++i) nxt[i] = ld4(src + oct * 4 + i * 32);
                }
                float a0 = 0.0f;
#pragma unroll
                for (int i = 0; i < 8; ++i) {
                    a0 = fmaf(cur[i].x, hreg2[i * 4 + 0], a0);
                    a0 = fmaf(cur[i].y, hreg2[i * 4 + 1], a0);
                    a0 = fmaf(cur[i].z, hreg2[i * 4 + 2], a0);
                    a0 = fmaf(cur[i].w, hreg2[i * 4 + 3], a0);
                }
                a0 += __shfl_xor(a0, 1); a0 += __shfl_xor(a0, 2); a0 += __shfl_xor(a0, 4);
                if (oct == 0) hgp[q * 128 + jg] = a0;
            };
#pragma unroll 1
            for (int q = 0; q < 4; q += 2) { p3(wA, wB, q); p3(wB, wA, q + 1); }
        }
        __syncthreads();
        // ---- phase 4: gs scores over compacted rows ----
        {
            const int uc = ucount_s;
            if (jg < uc) {
                const int r = ulist[jg];
                const float* gr = &grefb[(size_t)r * 256 + oct * 4];
                f32x4 g0[8];
#pragma unroll
                for (int i = 0; i < 8; ++i) g0[i] = ld4(gr + i * 32);
                float part = 0.0f;
#pragma unroll
                for (int i = 0; i < 8; ++i) {
                    const int d = i * 32 + oct * 4;
                    const f32x4 hh = ld4(&hgp[d]);
                    const f32x4 vv = ld4(&gv_lds[d]);
                    part = fmaf(ftanh_fast(g0[i].x + hh.x), vv.x, part);
                    part = fmaf(ftanh_fast(g0[i].y + hh.y), vv.y, part);
                    part = fmaf(ftanh_fast(g0[i].z + hh.z), vv.z, part);
                    part = fmaf(ftanh_fast(g0[i].w + hh.w), vv.w, part);
                }
                part += __shfl_xor(part, 1); part += __shfl_xor(part, 2); part += __shfl_xor(part, 4);
                if (oct == 0) sc_arr[r] = part * 0.0625f;
            }
        }
        __syncthreads();
        // ---- phase 5: softmax (wave 0) ----
        if (tid < 64) {
            float s0 = sc_arr[lane], s1 = sc_arr[lane + 64];
            float m = fmaxf(s0, s1);
#pragma unroll
            for (int mk = 1; mk < 64; mk <<= 1) m = fmaxf(m, __shfl_xor(m, mk));
            float e0 = expf(s0 - m), e1 = expf(s1 - m);
            e_arr[lane] = e0; e_arr[lane + 64] = e1;
            float z = e0 + e1;
#pragma unroll
            for (int mk = 1; mk < 64; mk <<= 1) z += __shfl_xor(z, mk);
            if (lane == 0) Z_s = z;
        }
        __syncthreads();
        // ---- phase 6: ctx partials over compacted rows (16 waves x 8) ----
        {
            const int uc = ucount_s;
            const int d4 = lane * 4;
            float ax = 0.0f, ay = 0.0f, az = 0.0f, aw = 0.0f;
            if (wid * 8 < uc) {
                f32x4 p0[8]; float ee[8];
#pragma unroll
                for (int i = 0; i < 8; ++i) {
                    const int k = wid * 8 + i;
                    const int kc = (k < uc) ? k : (uc - 1);
                    const int s = ulist[kc];
                    ee[i] = (k < uc) ? e_arr[s] : 0.0f;
                    p0[i] = ld4(&encPb[(size_t)s * 256 + d4]);
                }
#pragma unroll
                for (int i = 0; i < 8; ++i) {
                    ax = fmaf(p0[i].x, ee[i], ax); ay = fmaf(p0[i].y, ee[i], ay);
                    az = fmaf(p0[i].z, ee[i], az); aw = fmaf(p0[i].w, ee[i], aw);
                }
            }
            *reinterpret_cast<float4*>(&hp_half[wid][d4]) = make_float4(ax, ay, az, aw);
        }
        __syncthreads();
        if (tid < 256) {
            float s = 0.0f;
#pragma unroll
            for (int k = 0; k < 16; ++k) s += hp_half[k][tid];
            hp_lds[tid] = hgp[256 + tid] + s * frcp(Z_s);
        }
        __syncthreads();
        // ---- phase 7: ps scores over compacted rows ----
        {
            const int uc = ucount_s;
            if (jg < uc) {
                const int r = ulist[jg];
                const float* pr = &prefb[(size_t)r * 256 + oct * 4];
                f32x4 g0[8];
#pragma unroll
                for (int i = 0; i < 8; ++i) g0[i] = ld4(pr + i * 32);
                float part = 0.0f;
#pragma unroll
                for (int i = 0; i < 8; ++i) {
                    const int d = i * 32 + oct * 4;
                    const f32x4 hh = ld4(&hp_lds[d]);
                    const f32x4 vv = ld4(&pv_lds[d]);
                    part = fmaf(ftanh_fast(g0[i].x + hh.x), vv.x, part);
                    part = fmaf(ftanh_fast(g0[i].y + hh.y), vv.y, part);
                    part = fmaf(ftanh_fast(g0[i].z + hh.z), vv.z, part);
                    part = fmaf(ftanh_fast(g0[i].w + hh.w), vv.w, part);
                }
                part += __shfl_xor(part, 1); part += __shfl_xor(part, 2); part += __shfl_xor(part, 4);
                if (oct == 0) sc_arr[r] = part * 0.0625f;
            }
        }
        __syncthreads();
        // ---- phase 8: logits write + argmax (first-max semantics) ----
        if (tid < 128) {
            out_logits[((size_t)(b * SS + t)) * SS + tid] = sc_arr[tid];
        }
        if (tid < 64) {
            float v = sc_arr[lane];
            int idx = lane;
            float v2 = sc_arr[lane + 64];
            if (v2 > v) { v = v2; idx = lane + 64; }
#pragma unroll
            for (int mk = 1; mk < 64; mk <<= 1) {
                float ov = __shfl_xor(v, mk);
                int oi = __shfl_xor(idx, mk);
                if (ov > v || (ov == v && oi < idx)) { v = ov; idx = oi; }
            }
            if (lane == 0) {
                sel_s = idx;
                mask_lds[idx] = 1;
                out_ptrs[(size_t)b * SS + t] = (float)idx;
            }
        }
        __syncthreads();
    }
}

// =====================================================================
// host launcher
// =====================================================================
extern "C" void kernel_launch(void* const* d_in, const int* in_sizes, int n_in,
                              void* d_out, int out_size, void* d_ws, size_t ws_size,
                              hipStream_t stream)
{
    (void)in_sizes; (void)n_in; (void)out_size; (void)ws_size;
    const float* x      = (const float*)d_in[0];
    const float* proj_W = (const float*)d_in[1];
    const float* proj_b = (const float*)d_in[2];
    const float* ln_g   = (const float*)d_in[3];
    const float* ln_b   = (const float*)d_in[4];
    const float* Wih_f  = (const float*)d_in[5];
    const float* Whh_f  = (const float*)d_in[6];
    const float* bih_f  = (const float*)d_in[7];
    const float* bhh_f  = (const float*)d_in[8];
    const float* Wih_b  = (const float*)d_in[9];
    const float* Whh_b  = (const float*)d_in[10];
    const float* bih_b  = (const float*)d_in[11];
    const float* bhh_b  = (const float*)d_in[12];
    const float* Wih_d  = (const float*)d_in[13];
    const float* Whh_d  = (const float*)d_in[14];
    const float* bih_d  = (const float*)d_in[15];
    const float* bhh_d  = (const float*)d_in[16];
    const float* hb_W   = (const float*)d_in[17];
    const float* hb_b   = (const float*)d_in[18];
    const float* cb_W   = (const float*)d_in[19];
    const float* cb_b   = (const float*)d_in[20];
    const float* gW1    = (const float*)d_in[21];
    const float* gW2    = (const float*)d_in[22];
    const float* gv     = (const float*)d_in[23];
    const float* pW1    = (const float*)d_in[24];
    const float* pW2    = (const float*)d_in[25];
    const float* pv     = (const float*)d_in[26];

    float* ws = (float*)d_ws;
    const size_t o_hT    = 0;
    const size_t o_cT    = 65536;
    const size_t o_h0    = 131072;
    const size_t o_c0    = 163840;
    const size_t o_pre0  = 196608;
    const size_t o_emb   = 0;
    const size_t o_xf    = 4194304;
    const size_t o_xb    = o_xf + 16777216;
    const size_t o_enc   = o_xb + 16777216;
    const size_t o_encW  = o_xf;
    const size_t o_gref  = o_xb;
    const size_t o_pref  = o_xb + 4194304;
    const size_t o_encP  = o_xb + 8388608;

    float* emb  = ws + o_emb;
    float* xf   = ws + o_xf;
    float* xb   = ws + o_xb;
    float* enc  = ws + o_enc;
    float* hT   = ws + o_hT;
    float* cT   = ws + o_cT;
    float* h0b  = ws + o_h0;
    float* c0b  = ws + o_c0;
    float* pre0 = ws + o_pre0;
    float* encW = ws + o_encW;
    float* gref = ws + o_gref;
    float* pref = ws + o_pref;
    float* encP = ws + o_encP;

    float* out_logits = (float*)d_out;
    float* out_ptrs   = out_logits + (size_t)BB * SS * SS;

    // 1. emb
    k_proj_ln<<<BB * SS, 256, 0, stream>>>(x, proj_W, proj_b, ln_g, ln_b, emb);
    // 2-3. xf / xb  (bias = bih + bhh)
    {
        dim3 g(128, 8);
        k_gemm_nt<<<g, 256, 0, stream>>>(emb, 256, Wih_f, xf, 16384, 1024, 256, bih_f, bhh_f, 0);
        k_gemm_nt<<<g, 256, 0, stream>>>(emb, 256, Wih_b, xb, 16384, 1024, 256, bih_b, bhh_b, 0);
    }
    // 4. LSTM both directions: 256 WGs, one chain each
    k_lstm<<<256, 512, 0, stream>>>(Whh_f, Whh_b, xf, xb, enc, hT, cT);
    // 5-6. h0 / c0
    {
        dim3 g(1, 2);
        k_gemm_nt<<<g, 256, 0, stream>>>(hT, 512, hb_W, h0b, 128, 256, 512, hb_b, nullptr, 1);
        k_gemm_nt<<<g, 256, 0, stream>>>(cT, 512, cb_W, c0b, 128, 256, 512, cb_b, nullptr, 1);
    }
    // 7-10. attention precomputes
    {
        dim3 g2(128, 2);
        k_gemm_nt<<<g2, 256, 0, stream>>>(enc, 512, gW1, gref, 16384, 256, 512, nullptr, nullptr, 0);
        k_gemm_nt<<<g2, 256, 0, stream>>>(enc, 512, pW1, pref, 16384, 256, 512, nullptr, nullptr, 0);
        dim3 g1(128, 8);
        k_gemm_nt<<<g1, 256, 0, stream>>>(enc, 512, Wih_d, encW, 16384, 1024, 512, bih_d, bhh_d, 0);
        k_gemm_nt<<<g2, 256, 0, stream>>>(enc, 512, pW2, encP, 16384, 256, 256, nullptr, nullptr, 0);
    }
    // 11. pre0 = mean_s encW
    k_meanw<<<BB, 256, 0, stream>>>(encW, pre0);
    // 12. decoder: 128 WGs x 1024 threads, mask-compacted ref phases
    k_decoder<<<128, 1024, 0, stream>>>(Whh_d, gW2, pW2, gv, pv, gref, pref, encP, encW,
                                        pre0, h0b, c0b, out_logits, out_ptrs);
}